// Round 2
// baseline (9.870 us; speedup 1.0000x reference)
//
#include <hip/hip_runtime.h>

#define NQ 8
#define ROWS (16 * 4096)          // BATCH * SEQ
#define EMBED 768
#define NOUT (ROWS * NQ)          // 524288

__global__ __launch_bounds__(256) void qfe_kernel(const float* __restrict__ x,
                                                  const float* __restrict__ theta,
                                                  float* __restrict__ out) {
    int t = blockIdx.x * blockDim.x + threadIdx.x;   // one thread per output element
    if (t >= NOUT) return;
    int row = t >> 3;        // t / NQ
    int col = t & (NQ - 1);  // t % NQ

    float v  = x[(size_t)row * EMBED + col];
    float ct = cosf(theta[col]);   // theta: 32 B, L1-resident after first touch
    out[t] = cosf(v) * ct;
}

extern "C" void kernel_launch(void* const* d_in, const int* in_sizes, int n_in,
                              void* d_out, int out_size, void* d_ws, size_t ws_size,
                              hipStream_t stream) {
    const float* x     = (const float*)d_in[0];
    const float* theta = (const float*)d_in[1];
    float* out         = (float*)d_out;

    dim3 block(256);
    dim3 grid((NOUT + 255) / 256);   // 2048 blocks
    qfe_kernel<<<grid, block, 0, stream>>>(x, theta, out);
}